// Round 6
// baseline (104.573 us; speedup 1.0000x reference)
//
#include <hip/hip_runtime.h>
#include <stdint.h>

#define SL 4096
#define DM 1024
#define NH 16
#define HDIM 64

typedef short short8 __attribute__((ext_vector_type(8)));
typedef float f32x4 __attribute__((ext_vector_type(4)));

__device__ __forceinline__ unsigned short f2bf(float f) {
  unsigned int u = __float_as_uint(f);
  u += 0x7FFF + ((u >> 16) & 1);
  return (unsigned short)(u >> 16);
}
__device__ __forceinline__ float bf2f(unsigned short u) {
  return __uint_as_float((unsigned int)u << 16);
}
__device__ __forceinline__ float bflo(unsigned int u) { return __uint_as_float(u << 16); }
__device__ __forceinline__ float bfhi(unsigned int u) { return __uint_as_float(u & 0xffff0000u); }

__device__ __forceinline__ void gload_lds16(const void* g, void* l) {
  __builtin_amdgcn_global_load_lds((const __attribute__((address_space(1))) void*)g,
                                   (__attribute__((address_space(3))) void*)l, 16, 0, 0);
}

// ---------------- cast fp32 -> bf16 (x) ----------------
__global__ void cast4(const float* __restrict__ src, unsigned short* __restrict__ dst, int n4) {
  int i = blockIdx.x * blockDim.x + threadIdx.x;
  if (i >= n4) return;
  float4 v = ((const float4*)src)[i];
  ushort4 o = make_ushort4(f2bf(v.x), f2bf(v.y), f2bf(v.z), f2bf(v.w));
  ((ushort4*)dst)[i] = o;
}

// ---------------- cast all 4 weight matrices in one launch ----------------
__global__ void cast_weights(const float* __restrict__ Wq, const float* __restrict__ Wk,
                             const float* __restrict__ Wv, const float* __restrict__ Wo,
                             unsigned short* __restrict__ w3b, unsigned short* __restrict__ wob) {
  int i = blockIdx.x * blockDim.x + threadIdx.x;  // 0 .. 4*(DM*DM/4)-1
  int seg = i >> 18;                              // DM*DM/4 = 262144 = 2^18
  int off = i & 262143;
  const float* src = (seg == 0) ? Wq : (seg == 1) ? Wk : (seg == 2) ? Wv : Wo;
  unsigned short* dst = (seg < 3) ? (w3b + (size_t)seg * DM * DM) : wob;
  float4 v = ((const float4*)src)[off];
  ushort4 o = make_ushort4(f2bf(v.x), f2bf(v.y), f2bf(v.z), f2bf(v.w));
  ((ushort4*)dst)[off] = o;
}

// ---------------- bf16 MFMA GEMM: C[M,N] = A[M,K] * B[N,K]^T ----
// 128x128 tile, BK=32, 4 waves. 3-buffer LDS, counted-vmcnt pipeline (2 tiles
// in flight), raw s_barrier. K-slot XOR swizzle (both-sides, rule #21):
// linear LDS dest, pre-swizzled global source, swizzled ds_read.
template <bool BF16OUT, bool ROPE>
__global__ void gemm_bt(const unsigned short* __restrict__ A,
                        const unsigned short* __restrict__ B,
                        void* __restrict__ Cv,
                        int M, int N, int K, int ldc,
                        const float* __restrict__ fc, const float* __restrict__ fs) {
  __shared__ __align__(16) unsigned short As[3][128 * 32];
  __shared__ __align__(16) unsigned short Bs[3][128 * 32];
  const int tid  = threadIdx.x;
  const int w    = tid >> 6;
  const int lane = tid & 63;
  const int wr = w >> 1, wc = w & 1;
  const int brow = blockIdx.y * 128;
  const int bcol = blockIdx.x * 128;
  const int l4 = lane >> 2;                               // inner row (0..15) staged
  const int lkS = (((lane & 3) ^ ((lane >> 3) & 3))) * 8; // pre-swizzled global k-chunk
  const int lrow = lane & 15;                             // fragment row
  const int sw8 = (((lane >> 4) ^ ((lane >> 1) & 3))) * 8; // swizzled read slot (elems)
  const int c0 = w * 2;

  const unsigned short* Ag0 = A + (size_t)(brow + c0 * 16 + l4) * K + lkS;
  const unsigned short* Ag1 = A + (size_t)(brow + (c0 + 1) * 16 + l4) * K + lkS;
  const unsigned short* Bg0 = B + (size_t)(bcol + c0 * 16 + l4) * K + lkS;
  const unsigned short* Bg1 = B + (size_t)(bcol + (c0 + 1) * 16 + l4) * K + lkS;

  f32x4 acc[4][4] = {};
  const int NT = K >> 5;  // 32 for K=1024

  auto STAGE = [&](int t, int b) {
    const int k0 = t << 5;
    gload_lds16(Ag0 + k0, &As[b][c0 * 512]);
    gload_lds16(Ag1 + k0, &As[b][(c0 + 1) * 512]);
    gload_lds16(Bg0 + k0, &Bs[b][c0 * 512]);
    gload_lds16(Bg1 + k0, &Bs[b][(c0 + 1) * 512]);
  };
  auto COMPUTE = [&](int cur) {
    short8 af[4], bf[4];
#pragma unroll
    for (int m = 0; m < 4; ++m)
      af[m] = *(const short8*)&As[cur][(wr * 64 + m * 16 + lrow) * 32 + sw8];
#pragma unroll
    for (int n = 0; n < 4; ++n)
      bf[n] = *(const short8*)&Bs[cur][(wc * 64 + n * 16 + lrow) * 32 + sw8];
#pragma unroll
    for (int m = 0; m < 4; ++m)
#pragma unroll
      for (int n = 0; n < 4; ++n)
        acc[m][n] = __builtin_amdgcn_mfma_f32_16x16x32_bf16(af[m], bf[n], acc[m][n], 0, 0, 0);
  };

  STAGE(0, 0);
  STAGE(1, 1);
  for (int t = 0; t < NT - 1; ++t) {
    // stage(t) done when <= 1 stage (4 loads) outstanding
    asm volatile("s_waitcnt vmcnt(4)" ::: "memory");
    __builtin_amdgcn_sched_barrier(0);
    __builtin_amdgcn_s_barrier();
    __builtin_amdgcn_sched_barrier(0);
    if (t + 2 < NT) STAGE(t + 2, (t + 2) % 3);
    COMPUTE(t % 3);
  }
  asm volatile("s_waitcnt vmcnt(0)" ::: "memory");
  __builtin_amdgcn_sched_barrier(0);
  __builtin_amdgcn_s_barrier();
  __builtin_amdgcn_sched_barrier(0);
  COMPUTE((NT - 1) % 3);

  const int er = (lane >> 4) * 4;
  const int ec = lane & 15;

  if constexpr (ROPE) {
    // output cols [0,2048) are Q|K -> rotate pairs (even,odd col) = (even,odd lane)
    if (bcol + wc * 64 < 2048) {
#pragma unroll
      for (int n = 0; n < 4; ++n) {
        const int p = ((n * 16 + ec) & 63) >> 1;  // pair index within head
#pragma unroll
        for (int m = 0; m < 4; ++m) {
#pragma unroll
          for (int r = 0; r < 4; ++r) {
            const int row = brow + wr * 64 + m * 16 + er + r;
            float v = acc[m][n][r];
            float pv = __shfl_xor(v, 1);
            float cs = fc[row * 32 + p], sn = fs[row * 32 + p];
            acc[m][n][r] = (lane & 1) ? (pv * sn + v * cs) : (v * cs - pv * sn);
          }
        }
      }
    }
  }

#pragma unroll
  for (int m = 0; m < 4; ++m)
#pragma unroll
    for (int n = 0; n < 4; ++n) {
      const size_t roff = (size_t)(brow + wr * 64 + m * 16 + er) * ldc + (bcol + wc * 64 + n * 16 + ec);
      if constexpr (BF16OUT) {
        unsigned short* cp = (unsigned short*)Cv + roff;
#pragma unroll
        for (int r = 0; r < 4; ++r) cp[(size_t)r * ldc] = f2bf(acc[m][n][r]);
      } else {
        float* cp = (float*)Cv + roff;
#pragma unroll
        for (int r = 0; r < 4; ++r) cp[(size_t)r * ldc] = acc[m][n][r];
      }
    }
}

// ---------------- attention row 0, flash-split: 128 partials/head ----------
__global__ __launch_bounds__(64)
void attn_row0_part(const unsigned short* __restrict__ qkv, float* __restrict__ prt) {
  const int p = blockIdx.x;
  const int h = blockIdx.y;
  const int lane = threadIdx.x;
  const float q = bf2f(qkv[h * 64 + lane]);
  float m = -1e30f, s = 0.f, o = 0.f;
  const int j0 = p * 32;
  for (int jj = 0; jj < 32; ++jj) {
    const int j = j0 + jj;
    float kv = bf2f(qkv[(size_t)j * 3072 + 1024 + h * 64 + lane]);
    float pr = q * kv;
#pragma unroll
    for (int off = 32; off; off >>= 1) pr += __shfl_xor(pr, off);
    pr *= 0.125f;
    float mn = fmaxf(m, pr);
    float c = __expf(m - mn);
    float e = __expf(pr - mn);
    float v = bf2f(qkv[(size_t)j * 3072 + 2048 + h * 64 + lane]);
    s = s * c + e;
    o = o * c + e * v;
    m = mn;
  }
  float* dst = prt + ((size_t)h * 128 + p) * 72;
  if (lane == 0) { dst[0] = m; dst[1] = s; }
  dst[2 + lane] = o;
}

// ---------------- row-0 combine: 16 blocks, wave-parallel over partials ----
__global__ __launch_bounds__(64)
void attn_row0_combine(const float* __restrict__ prt, unsigned short* __restrict__ atb) {
  const int h = blockIdx.x;
  const int lane = threadIdx.x;
  const float* base = prt + (size_t)h * 128 * 72;
  __shared__ float cbuf[128];
  float m0 = base[lane * 72];
  float m1 = base[(lane + 64) * 72];
  float M = fmaxf(m0, m1);
#pragma unroll
  for (int off = 32; off; off >>= 1) M = fmaxf(M, __shfl_xor(M, off));
  float c0 = __expf(m0 - M), c1 = __expf(m1 - M);
  float ls = base[lane * 72 + 1] * c0 + base[(lane + 64) * 72 + 1] * c1;
#pragma unroll
  for (int off = 32; off; off >>= 1) ls += __shfl_xor(ls, off);
  cbuf[lane] = c0;
  cbuf[lane + 64] = c1;
  __syncthreads();
  float o = 0.f;
#pragma unroll 8
  for (int p = 0; p < 128; ++p) o += cbuf[p] * base[p * 72 + 2 + lane];
  atb[h * 64 + lane] = f2bf(o / ls);
}

// ---------------- attention rows 1..L-1 (one wave per row, 16 heads/wave) ----
__global__ __launch_bounds__(256)
void attn_main(const unsigned short* __restrict__ qkv, unsigned short* __restrict__ atb) {
  const int i = blockIdx.x * 4 + (threadIdx.x >> 6) + 1;
  if (i >= SL) return;
  const int lane = threadIdx.x & 63;
  const unsigned short* rowQ = qkv + (size_t)i * 3072 + lane * 16;

  float q[16];
  {
    uint4 a = *(const uint4*)rowQ;
    uint4 b = *(const uint4*)(rowQ + 8);
    unsigned int uu[8] = {a.x, a.y, a.z, a.w, b.x, b.y, b.z, b.w};
#pragma unroll
    for (int c = 0; c < 8; ++c) { q[2 * c] = bflo(uu[c]); q[2 * c + 1] = bfhi(uu[c]); }
  }

  float sc[9];
#pragma unroll
  for (int t = 0; t < 9; ++t) {
    int j = (t == 0) ? 0 : (i - 8 + t);
    bool valid = (t == 0) || (j >= 1);
    int jc = valid ? j : 0;
    const unsigned short* pk = qkv + (size_t)jc * 3072 + 1024 + lane * 16;
    uint4 a = *(const uint4*)pk;
    uint4 b = *(const uint4*)(pk + 8);
    unsigned int uu[8] = {a.x, a.y, a.z, a.w, b.x, b.y, b.z, b.w};
    float pr = 0.f;
#pragma unroll
    for (int c = 0; c < 8; ++c) pr += bflo(uu[c]) * q[2 * c] + bfhi(uu[c]) * q[2 * c + 1];
    pr += __shfl_xor(pr, 1);
    pr += __shfl_xor(pr, 2);
    sc[t] = valid ? pr * 0.125f : -1e30f;
  }

  float mx = sc[0];
#pragma unroll
  for (int t = 1; t < 9; ++t) mx = fmaxf(mx, sc[t]);
  float s = 0.f;
#pragma unroll
  for (int t = 0; t < 9; ++t) { float e = __expf(sc[t] - mx); sc[t] = e; s += e; }
  const float inv = 1.0f / s;

  float o[16] = {};
#pragma unroll
  for (int t = 0; t < 9; ++t) {
    int j = (t == 0) ? 0 : (i - 8 + t);
    bool valid = (t == 0) || (j >= 1);
    int jc = valid ? j : 0;
    const unsigned short* pv = qkv + (size_t)jc * 3072 + 2048 + lane * 16;
    uint4 a = *(const uint4*)pv;
    uint4 b = *(const uint4*)(pv + 8);
    unsigned int uu[8] = {a.x, a.y, a.z, a.w, b.x, b.y, b.z, b.w};
#pragma unroll
    for (int c = 0; c < 8; ++c) {
      o[2 * c]     += sc[t] * bflo(uu[c]);
      o[2 * c + 1] += sc[t] * bfhi(uu[c]);
    }
  }

  unsigned int wv[8];
#pragma unroll
  for (int c = 0; c < 8; ++c)
    wv[c] = (unsigned int)f2bf(o[2 * c] * inv) | ((unsigned int)f2bf(o[2 * c + 1] * inv) << 16);
  unsigned short* po = atb + (size_t)i * 1024 + lane * 16;
  uint4 s0; s0.x = wv[0]; s0.y = wv[1]; s0.z = wv[2]; s0.w = wv[3];
  uint4 s1; s1.x = wv[4]; s1.y = wv[5]; s1.z = wv[6]; s1.w = wv[7];
  *(uint4*)po = s0;
  *(uint4*)(po + 8) = s1;
}

extern "C" void kernel_launch(void* const* d_in, const int* in_sizes, int n_in,
                              void* d_out, int out_size, void* d_ws, size_t ws_size,
                              hipStream_t stream) {
  const float* x  = (const float*)d_in[0];
  const float* Wq = (const float*)d_in[1];
  const float* Wk = (const float*)d_in[2];
  const float* Wv = (const float*)d_in[3];
  const float* Wo = (const float*)d_in[4];
  const float* fc = (const float*)d_in[5];
  const float* fs = (const float*)d_in[6];
  float* out = (float*)d_out;

  char* ws = (char*)d_ws;
  unsigned short* xb   = (unsigned short*)(ws);                      // 8 MB  bf16 x
  unsigned short* w3b  = (unsigned short*)(ws + ((size_t)8 << 20));  // 6 MB  bf16 [Wq;Wk;Wv]
  unsigned short* wob  = (unsigned short*)(ws + ((size_t)14 << 20)); // 2 MB  bf16 Wo
  unsigned short* qkvb = (unsigned short*)(ws + ((size_t)16 << 20)); // 24 MB bf16 QKV (roped)
  unsigned short* atb  = (unsigned short*)(ws + ((size_t)40 << 20)); // 8 MB  bf16 attn out
  float*          prt  = (float*)(ws + ((size_t)48 << 20));          // 0.6 MB row0 partials

  cast4<<<(SL * DM / 4 + 255) / 256, 256, 0, stream>>>(x, xb, SL * DM / 4);
  cast_weights<<<(4 * DM * DM / 4) / 256, 256, 0, stream>>>(Wq, Wk, Wv, Wo, w3b, wob);

  dim3 g1(3072 / 128, SL / 128);
  gemm_bt<true, true><<<g1, 256, 0, stream>>>(xb, w3b, (void*)qkvb, SL, 3072, DM, 3072, fc, fs);

  attn_row0_part<<<dim3(128, NH), 64, 0, stream>>>(qkvb, prt);
  attn_row0_combine<<<NH, 64, 0, stream>>>(prt, atb);
  attn_main<<<1024, 256, 0, stream>>>(qkvb, atb);

  dim3 g2(DM / 128, SL / 128);
  gemm_bt<false, false><<<g2, 256, 0, stream>>>(atb, wob, (void*)out, SL, DM, DM, DM, nullptr, nullptr);
}

// Round 7
// 102.354 us; speedup vs baseline: 1.0217x; 1.0217x over previous
//
#include <hip/hip_runtime.h>
#include <stdint.h>

#define SL 4096
#define DM 1024
#define NH 16
#define HDIM 64

typedef short short8 __attribute__((ext_vector_type(8)));
typedef float f32x4 __attribute__((ext_vector_type(4)));

__device__ __forceinline__ unsigned short f2bf(float f) {
  unsigned int u = __float_as_uint(f);
  u += 0x7FFF + ((u >> 16) & 1);
  return (unsigned short)(u >> 16);
}
__device__ __forceinline__ float bf2f(unsigned short u) {
  return __uint_as_float((unsigned int)u << 16);
}
__device__ __forceinline__ float bflo(unsigned int u) { return __uint_as_float(u << 16); }
__device__ __forceinline__ float bfhi(unsigned int u) { return __uint_as_float(u & 0xffff0000u); }

__device__ __forceinline__ void gload_lds16(const void* g, void* l) {
  __builtin_amdgcn_global_load_lds((const __attribute__((address_space(1))) void*)g,
                                   (__attribute__((address_space(3))) void*)l, 16, 0, 0);
}

// ---------------- fused cast: x (1M float4) + 4 weight mats (1M float4) ----
__global__ void cast_all(const float* __restrict__ x,
                         const float* __restrict__ Wq, const float* __restrict__ Wk,
                         const float* __restrict__ Wv, const float* __restrict__ Wo,
                         unsigned short* __restrict__ xb,
                         unsigned short* __restrict__ w3b, unsigned short* __restrict__ wob) {
  int i = blockIdx.x * blockDim.x + threadIdx.x;  // 0 .. 2*2^20-1
  const float* src;
  unsigned short* dst;
  int off;
  if (i < (1 << 20)) {
    src = x; dst = xb; off = i;
  } else {
    int wsel = i - (1 << 20);
    int seg = wsel >> 18;                         // 0..3
    off = wsel & 262143;
    src = (seg == 0) ? Wq : (seg == 1) ? Wk : (seg == 2) ? Wv : Wo;
    dst = (seg < 3) ? (w3b + (size_t)seg * DM * DM) : wob;
  }
  float4 v = ((const float4*)src)[off];
  ushort4 o = make_ushort4(f2bf(v.x), f2bf(v.y), f2bf(v.z), f2bf(v.w));
  ((ushort4*)dst)[off] = o;
}

// ---------------- bf16 MFMA GEMM: C[M,N] = A[M,K] * B[N,K]^T ----
// Templated tile BMxBN (wave-tile 64x64), BK=32, double-buffered LDS,
// 1 barrier per K-step, k-slot XOR swizzle (both-sides), XCD-chunked
// block swizzle (grid must be divisible by 8).
template <int BM, int BN, bool BF16OUT, bool ROPE>
__global__ void gemm_bt(const unsigned short* __restrict__ A,
                        const unsigned short* __restrict__ B,
                        void* __restrict__ Cv,
                        int M, int N, int K, int ldc,
                        const float* __restrict__ fc, const float* __restrict__ fs) {
  constexpr int WM = BM / 64, WN = BN / 64, W = WM * WN;
  constexpr int ACW = BM / 16 / W;   // A 16-row chunks staged per wave
  constexpr int BCW = BN / 16 / W;   // B 16-row chunks staged per wave
  __shared__ __align__(16) unsigned short As[2][BM * 32];
  __shared__ __align__(16) unsigned short Bs[2][BN * 32];
  const int tid  = threadIdx.x;
  const int w    = tid >> 6;
  const int lane = tid & 63;
  const int wr = w / WN, wc = w % WN;

  // bijective XCD swizzle (total blocks divisible by 8)
  const int gx = gridDim.x;
  const int total = gx * gridDim.y;
  const int lin = blockIdx.y * gx + blockIdx.x;
  const int swz = (lin & 7) * (total >> 3) + (lin >> 3);
  const int brow = (swz / gx) * BM;
  const int bcol = (swz % gx) * BN;

  const int l4 = lane >> 2;                                // row within 16-row chunk
  const int lkS = (((lane & 3) ^ ((lane >> 3) & 3))) * 8;  // pre-swizzled global k-chunk
  const int lrow = lane & 15;
  const int sw8 = (((lane >> 4) ^ ((lane >> 1) & 3))) * 8; // swizzled read slot

  const unsigned short* Ag[ACW];
  const unsigned short* Bg[BCW];
#pragma unroll
  for (int c = 0; c < ACW; ++c)
    Ag[c] = A + (size_t)(brow + (w * ACW + c) * 16 + l4) * K + lkS;
#pragma unroll
  for (int c = 0; c < BCW; ++c)
    Bg[c] = B + (size_t)(bcol + (w * BCW + c) * 16 + l4) * K + lkS;

  f32x4 acc[4][4] = {};
  const int NT = K >> 5;

  auto STAGE = [&](int t, int b) {
    const int k0 = t << 5;
#pragma unroll
    for (int c = 0; c < ACW; ++c) gload_lds16(Ag[c] + k0, &As[b][(w * ACW + c) * 512]);
#pragma unroll
    for (int c = 0; c < BCW; ++c) gload_lds16(Bg[c] + k0, &Bs[b][(w * BCW + c) * 512]);
  };
  auto COMPUTE = [&](int cur) {
    short8 af[4], bf[4];
#pragma unroll
    for (int m = 0; m < 4; ++m)
      af[m] = *(const short8*)&As[cur][(wr * 64 + m * 16 + lrow) * 32 + sw8];
#pragma unroll
    for (int n = 0; n < 4; ++n)
      bf[n] = *(const short8*)&Bs[cur][(wc * 64 + n * 16 + lrow) * 32 + sw8];
#pragma unroll
    for (int m = 0; m < 4; ++m)
#pragma unroll
      for (int n = 0; n < 4; ++n)
        acc[m][n] = __builtin_amdgcn_mfma_f32_16x16x32_bf16(af[m], bf[n], acc[m][n], 0, 0, 0);
  };

  STAGE(0, 0);
  for (int t = 0; t < NT; ++t) {
    const int cur = t & 1;
    __syncthreads();               // stage(t) landed
    if (t + 1 < NT) STAGE(t + 1, cur ^ 1);
    COMPUTE(cur);
  }

  const int er = (lane >> 4) * 4;
  const int ec = lane & 15;

  if constexpr (ROPE) {
    if (bcol + wc * 64 < 2048) {
#pragma unroll
      for (int n = 0; n < 4; ++n) {
        const int p = ((n * 16 + ec) & 63) >> 1;
#pragma unroll
        for (int m = 0; m < 4; ++m) {
#pragma unroll
          for (int r = 0; r < 4; ++r) {
            const int row = brow + wr * 64 + m * 16 + er + r;
            float v = acc[m][n][r];
            float pv = __shfl_xor(v, 1);
            float cs = fc[row * 32 + p], sn = fs[row * 32 + p];
            acc[m][n][r] = (lane & 1) ? (pv * sn + v * cs) : (v * cs - pv * sn);
          }
        }
      }
    }
  }

#pragma unroll
  for (int m = 0; m < 4; ++m)
#pragma unroll
    for (int n = 0; n < 4; ++n) {
      const size_t roff = (size_t)(brow + wr * 64 + m * 16 + er) * ldc + (bcol + wc * 64 + n * 16 + ec);
      if constexpr (BF16OUT) {
        unsigned short* cp = (unsigned short*)Cv + roff;
#pragma unroll
        for (int r = 0; r < 4; ++r) cp[(size_t)r * ldc] = f2bf(acc[m][n][r]);
      } else {
        float* cp = (float*)Cv + roff;
#pragma unroll
        for (int r = 0; r < 4; ++r) cp[(size_t)r * ldc] = acc[m][n][r];
      }
    }
}

// ---------------- fused attention: rows 1..L-1 + row-0 flash partials ------
// blocks [0,1024): one wave per row i (16 heads/wave, lane: head=l>>2, 16 d-elems)
// blocks [1024,1536): row-0 partials, one wave per (chunk p, head h)
__global__ __launch_bounds__(256)
void attn_fused(const unsigned short* __restrict__ qkv, unsigned short* __restrict__ atb,
                float* __restrict__ prt) {
  const int wid = threadIdx.x >> 6;
  const int lane = threadIdx.x & 63;
  if (blockIdx.x >= 1024) {
    // ---- row-0 partial: wave-unit u in [0,2048) -> p = u&127, h = u>>7
    const int u = (blockIdx.x - 1024) * 4 + wid;
    const int p = u & 127, h = u >> 7;
    const float q = bf2f(qkv[h * 64 + lane]);
    float m = -1e30f, s = 0.f, o = 0.f;
    const int j0 = p * 32;
    for (int jj = 0; jj < 32; ++jj) {
      const int j = j0 + jj;
      float kv = bf2f(qkv[(size_t)j * 3072 + 1024 + h * 64 + lane]);
      float pr = q * kv;
#pragma unroll
      for (int off = 32; off; off >>= 1) pr += __shfl_xor(pr, off);
      pr *= 0.125f;
      float mn = fmaxf(m, pr);
      float c = __expf(m - mn);
      float e = __expf(pr - mn);
      float v = bf2f(qkv[(size_t)j * 3072 + 2048 + h * 64 + lane]);
      s = s * c + e;
      o = o * c + e * v;
      m = mn;
    }
    float* dst = prt + ((size_t)h * 128 + p) * 72;
    if (lane == 0) { dst[0] = m; dst[1] = s; }
    dst[2 + lane] = o;
    return;
  }

  const int i = blockIdx.x * 4 + wid + 1;
  if (i >= SL) return;
  const unsigned short* rowQ = qkv + (size_t)i * 3072 + lane * 16;

  float q[16];
  {
    uint4 a = *(const uint4*)rowQ;
    uint4 b = *(const uint4*)(rowQ + 8);
    unsigned int uu[8] = {a.x, a.y, a.z, a.w, b.x, b.y, b.z, b.w};
#pragma unroll
    for (int c = 0; c < 8; ++c) { q[2 * c] = bflo(uu[c]); q[2 * c + 1] = bfhi(uu[c]); }
  }

  float sc[9];
#pragma unroll
  for (int t = 0; t < 9; ++t) {
    int j = (t == 0) ? 0 : (i - 8 + t);
    bool valid = (t == 0) || (j >= 1);
    int jc = valid ? j : 0;
    const unsigned short* pk = qkv + (size_t)jc * 3072 + 1024 + lane * 16;
    uint4 a = *(const uint4*)pk;
    uint4 b = *(const uint4*)(pk + 8);
    unsigned int uu[8] = {a.x, a.y, a.z, a.w, b.x, b.y, b.z, b.w};
    float pr = 0.f;
#pragma unroll
    for (int c = 0; c < 8; ++c) pr += bflo(uu[c]) * q[2 * c] + bfhi(uu[c]) * q[2 * c + 1];
    pr += __shfl_xor(pr, 1);
    pr += __shfl_xor(pr, 2);
    sc[t] = valid ? pr * 0.125f : -1e30f;
  }

  float mx = sc[0];
#pragma unroll
  for (int t = 1; t < 9; ++t) mx = fmaxf(mx, sc[t]);
  float s = 0.f;
#pragma unroll
  for (int t = 0; t < 9; ++t) { float e = __expf(sc[t] - mx); sc[t] = e; s += e; }
  const float inv = 1.0f / s;

  float o[16] = {};
#pragma unroll
  for (int t = 0; t < 9; ++t) {
    int j = (t == 0) ? 0 : (i - 8 + t);
    bool valid = (t == 0) || (j >= 1);
    int jc = valid ? j : 0;
    const unsigned short* pv = qkv + (size_t)jc * 3072 + 2048 + lane * 16;
    uint4 a = *(const uint4*)pv;
    uint4 b = *(const uint4*)(pv + 8);
    unsigned int uu[8] = {a.x, a.y, a.z, a.w, b.x, b.y, b.z, b.w};
#pragma unroll
    for (int c = 0; c < 8; ++c) {
      o[2 * c]     += sc[t] * bflo(uu[c]);
      o[2 * c + 1] += sc[t] * bfhi(uu[c]);
    }
  }

  unsigned int wv[8];
#pragma unroll
  for (int c = 0; c < 8; ++c)
    wv[c] = (unsigned int)f2bf(o[2 * c] * inv) | ((unsigned int)f2bf(o[2 * c + 1] * inv) << 16);
  unsigned short* po = atb + (size_t)i * 1024 + lane * 16;
  uint4 s0; s0.x = wv[0]; s0.y = wv[1]; s0.z = wv[2]; s0.w = wv[3];
  uint4 s1; s1.x = wv[4]; s1.y = wv[5]; s1.z = wv[6]; s1.w = wv[7];
  *(uint4*)po = s0;
  *(uint4*)(po + 8) = s1;
}

// ---------------- row-0 combine: 16 blocks, wave-parallel over partials ----
__global__ __launch_bounds__(64)
void attn_row0_combine(const float* __restrict__ prt, unsigned short* __restrict__ atb) {
  const int h = blockIdx.x;
  const int lane = threadIdx.x;
  const float* base = prt + (size_t)h * 128 * 72;
  __shared__ float cbuf[128];
  float m0 = base[lane * 72];
  float m1 = base[(lane + 64) * 72];
  float M = fmaxf(m0, m1);
#pragma unroll
  for (int off = 32; off; off >>= 1) M = fmaxf(M, __shfl_xor(M, off));
  float c0 = __expf(m0 - M), c1 = __expf(m1 - M);
  float ls = base[lane * 72 + 1] * c0 + base[(lane + 64) * 72 + 1] * c1;
#pragma unroll
  for (int off = 32; off; off >>= 1) ls += __shfl_xor(ls, off);
  cbuf[lane] = c0;
  cbuf[lane + 64] = c1;
  __syncthreads();
  float o = 0.f;
#pragma unroll 8
  for (int p = 0; p < 128; ++p) o += cbuf[p] * base[p * 72 + 2 + lane];
  atb[h * 64 + lane] = f2bf(o / ls);
}

extern "C" void kernel_launch(void* const* d_in, const int* in_sizes, int n_in,
                              void* d_out, int out_size, void* d_ws, size_t ws_size,
                              hipStream_t stream) {
  const float* x  = (const float*)d_in[0];
  const float* Wq = (const float*)d_in[1];
  const float* Wk = (const float*)d_in[2];
  const float* Wv = (const float*)d_in[3];
  const float* Wo = (const float*)d_in[4];
  const float* fc = (const float*)d_in[5];
  const float* fs = (const float*)d_in[6];
  float* out = (float*)d_out;

  char* ws = (char*)d_ws;
  unsigned short* xb   = (unsigned short*)(ws);                      // 8 MB  bf16 x
  unsigned short* w3b  = (unsigned short*)(ws + ((size_t)8 << 20));  // 6 MB  bf16 [Wq;Wk;Wv]
  unsigned short* wob  = (unsigned short*)(ws + ((size_t)14 << 20)); // 2 MB  bf16 Wo
  unsigned short* qkvb = (unsigned short*)(ws + ((size_t)16 << 20)); // 24 MB bf16 QKV (roped)
  unsigned short* atb  = (unsigned short*)(ws + ((size_t)40 << 20)); // 8 MB  bf16 attn out
  float*          prt  = (float*)(ws + ((size_t)48 << 20));          // 0.6 MB row0 partials

  cast_all<<<(2 * (1 << 20)) / 256, 256, 0, stream>>>(x, Wq, Wk, Wv, Wo, xb, w3b, wob);

  dim3 g1(3072 / 128, SL / 256);   // 24 x 16 = 384 blocks, 256x128 tile
  gemm_bt<256, 128, true, true><<<g1, 512, 0, stream>>>(xb, w3b, (void*)qkvb, SL, 3072, DM, 3072, fc, fs);

  attn_fused<<<1536, 256, 0, stream>>>(qkvb, atb, prt);
  attn_row0_combine<<<NH, 64, 0, stream>>>(prt, atb);

  dim3 g2(DM / 128, SL / 128);     // 8 x 32 = 256 blocks, 128x128 tile
  gemm_bt<128, 128, false, false><<<g2, 256, 0, stream>>>(atb, wob, (void*)out, SL, DM, DM, DM, nullptr, nullptr);
}